// Round 2
// baseline (431.180 us; speedup 1.0000x reference)
//
#include <hip/hip_runtime.h>
#include <stdint.h>

// ---------------------------------------------------------------------------
// GSDepthRankingLoss on MI355X — R1: compaction + 32-bit sort keys + vector
// crop loads. JAX threefry (partitionable mode) verified bit-exact in R0.
// ---------------------------------------------------------------------------

#define IMG_W 1920
#define IMG_H 1080
#define N_SAMP 518400         // int(1920*1080*0.25)
#define RADIUS 3
#define PAD_VAL (-1000000.0f)

struct Keys { uint32_t k[5][2][2]; };  // [randint id][k1|k2][key word]

// Threefry-2x32, 20 rounds (Random123 / JAX-compatible).
static __host__ __device__ inline void tf2x32(uint32_t k0, uint32_t k1,
                                              uint32_t x0, uint32_t x1,
                                              uint32_t& o0, uint32_t& o1)
{
  const uint32_t ks2 = k0 ^ k1 ^ 0x1BD11BDAu;
  x0 += k0; x1 += k1;
#define TFR(r) { x0 += x1; x1 = (x1 << (r)) | (x1 >> (32 - (r))); x1 ^= x0; }
  TFR(13) TFR(15) TFR(26) TFR(6)
  x0 += k1;  x1 += ks2 + 1u;
  TFR(17) TFR(29) TFR(16) TFR(24)
  x0 += ks2; x1 += k0 + 2u;
  TFR(13) TFR(15) TFR(26) TFR(6)
  x0 += k0;  x1 += k1 + 3u;
  TFR(17) TFR(29) TFR(16) TFR(24)
  x0 += k1;  x1 += ks2 + 4u;
  TFR(13) TFR(15) TFR(26) TFR(6)
  x0 += ks2; x1 += k0 + 5u;
#undef TFR
  o0 = x0; o1 = x1;
}

__device__ __forceinline__ uint32_t jrbits(const uint32_t kk[2], uint32_t f)
{
  uint32_t a, b;
  tf2x32(kk[0], kk[1], 0u, f, a, b);   // partitionable: counts = (0, f)
  return a ^ b;                        // 32-bit fold
}

__device__ __forceinline__ uint32_t jrandint(const Keys& K, int r, uint32_t f,
                                             uint32_t span)
{
  const uint32_t hi = jrbits(K.k[r][0], f);
  const uint32_t lo = jrbits(K.k[r][1], f);
  uint32_t m = 65536u % span;
  m = (m * m) % span;
  return ((hi % span) * m + (lo % span)) % span;
}

static void compute_keys(Keys& K)
{
  uint32_t ks[5][2];
  for (uint32_t t = 0; t < 5; t++) {
    uint32_t a, b; tf2x32(0u, 42u, 0u, t, a, b);   // split of key(42)
    ks[t][0] = a; ks[t][1] = b;
  }
  for (int r = 0; r < 5; r++) {                    // randint's internal _split
    uint32_t a, b;
    tf2x32(ks[r][0], ks[r][1], 0u, 0u, a, b); K.k[r][0][0] = a; K.k[r][0][1] = b;
    tf2x32(ks[r][0], ks[r][1], 0u, 1u, a, b); K.k[r][1][0] = a; K.k[r][1][1] = b;
  }
}

// triangular 15-slot insertion step (min/max network, 2 VALU per live slot)
__device__ __forceinline__ void ins15(uint32_t* arr, uint32_t key, int depth)
{
#pragma unroll
  for (int t = 0; t < 15; t++) {
    if (t < depth) {
      const uint32_t lo = min(key, arr[t]);
      const uint32_t hi = max(key, arr[t]);
      arr[t] = lo; key = hi;
    }
  }
}

// Find the nbr-th nearest neighbour (by |depth - sd|, stable position tie)
// of crop centered at (syj,sxj). Returns flat index.
__device__ __forceinline__ int crop_neighbor(const float* __restrict__ tgt,
                                             int syj, int sxj, float sdj,
                                             uint32_t nbr)
{
  uint32_t arr[15];
#pragma unroll
  for (int t = 0; t < 15; t++) arr[t] = 0xFFFFFFFFu;

  const bool interior = (syj >= RADIUS) && (syj <= IMG_H - 1 - RADIUS) &&
                        (sxj >= RADIUS) && (sxj <= IMG_W - 5);
  if (interior) {
#pragma unroll
    for (int ry = 0; ry < 7; ry++) {
      const float* rowp = tgt + (syj - RADIUS + ry) * IMG_W + sxj;
      float v[8];
      __builtin_memcpy(v, rowp - 3, 32);  // 8 floats, align-4, -> 2x dwordx4
#pragma unroll
      for (int rx = 0; rx < 7; rx++) {
        const int q = ry * 7 + rx;
        const uint32_t key =
            (__float_as_uint(v[rx] - sdj) & 0x7FFFFFC0u) | (uint32_t)q;
        ins15(arr, key, (q + 1 < 15) ? (q + 1) : 15);
      }
    }
  } else {
    // rare (~3e-4 of crops): guarded scalar path with PAD semantics
    int q = 0;
    for (int ry = 0; ry < 7; ry++) {
      const int yy = syj - RADIUS + ry;
      const bool rok = (yy >= 0) && (yy < IMG_H);
      const float* rowp = tgt + yy * IMG_W;
      for (int rx = 0; rx < 7; rx++, q++) {
        const int xx = sxj - RADIUS + rx;
        float v = PAD_VAL;
        if (rok && xx >= 0 && xx < IMG_W) v = rowp[xx];
        const uint32_t key =
            (__float_as_uint(v - sdj) & 0x7FFFFFC0u) | (uint32_t)q;
        ins15(arr, key, (q + 1 < 15) ? (q + 1) : 15);
      }
    }
  }

  uint32_t relkey = 0;
#pragma unroll
  for (int t = 1; t < 15; t++)
    if ((uint32_t)t == nbr) relkey = arr[t];
  const uint32_t rel = relkey & 63u;
  const int ny = syj - RADIUS + (int)(rel / 7u);
  const int nx = sxj - RADIUS + (int)(rel % 7u);
  return ny * IMG_W + nx;
}

// ---------------- Phase A: PRNG + sample mask + wave compaction -------------
__global__ __launch_bounds__(256) void gs_sample(
    const int* __restrict__ vmask,
    uint32_t* __restrict__ wcount,
    unsigned long long* __restrict__ wlist,
    Keys K)
{
  const int i = blockIdx.x * blockDim.x + threadIdx.x;
  bool ok = false;
  uint32_t sy0 = 0, sx0 = 0, sy1 = 0, sx1 = 0;
  if (i < N_SAMP) {
    const uint32_t ui = (uint32_t)i;
    const uint32_t syb = jrandint(K, 0, ui, 840u);    // H - 240
    const uint32_t sxb = jrandint(K, 1, ui, 1680u);   // W - 240
    sy0 = syb + jrandint(K, 2, 2u * ui,      240u);
    sy1 = syb + jrandint(K, 2, 2u * ui + 1u, 240u);
    sx0 = sxb + jrandint(K, 3, 2u * ui,      240u);
    sx1 = sxb + jrandint(K, 3, 2u * ui + 1u, 240u);
    ok = (vmask[sy0 * IMG_W + sx0] != 0) && (vmask[sy1 * IMG_W + sx1] != 0);
  }

  const unsigned long long ball = __ballot(ok);
  const uint32_t lane = threadIdx.x & 63u;
  const uint32_t prefix = __popcll(ball & ((1ull << lane) - 1ull));
  uint32_t base = 0;
  if (lane == 0 && ball)
    base = atomicAdd(wcount, (uint32_t)__popcll(ball));
  base = __shfl((int)base, 0);
  if (ok) {
    const unsigned long long e =
        ((unsigned long long)(uint32_t)i << 44) |
        ((unsigned long long)sy0 << 33) | ((unsigned long long)sx0 << 22) |
        ((unsigned long long)sy1 << 11) | (unsigned long long)sx1;
    wlist[base + prefix] = e;
  }
}

// ---------------- Phase B: crops + kNN select + loss on compacted list ------
__global__ __launch_bounds__(256) void gs_crop(
    const float* __restrict__ tgt,
    const float* __restrict__ rnd,
    const int*   __restrict__ vmask,
    const uint32_t* __restrict__ wcount,
    const unsigned long long* __restrict__ wlist,
    float* __restrict__ acc,
    Keys K)
{
  const uint32_t n = *wcount;
  const uint32_t tid = blockIdx.x * blockDim.x + threadIdx.x;
  float rank_c = 0.f, cont_c = 0.f, cnt_c = 0.f;

  if (tid < n) {
    const unsigned long long e = wlist[tid];
    const int sx1 = (int)(e & 2047u),          sy1 = (int)((e >> 11) & 2047u);
    const int sx0 = (int)((e >> 22) & 2047u),  sy0 = (int)((e >> 33) & 2047u);
    const uint32_t ui = (uint32_t)(e >> 44);
    const int sy[2] = { sy0, sy1 }, sx[2] = { sx0, sx1 };

    int sidx[2], nidx[2];
    float sd[2];
    bool nm = true;
#pragma unroll
    for (int j = 0; j < 2; j++) {
      sidx[j] = sy[j] * IMG_W + sx[j];
      sd[j] = tgt[sidx[j]];
      const uint32_t nbr =
          1u + jrandint(K, 4, 2u * ui + (uint32_t)j, 14u);  // [1,15)
      nidx[j] = crop_neighbor(tgt, sy[j], sx[j], sd[j], nbr);
      nm = nm && (vmask[nidx[j]] != 0);
    }

    if (nm) {
      const float r0 = rnd[sidx[0]], r1 = rnd[sidx[1]];
      const float q0 = rnd[nidx[0]], q1 = rnd[nidx[1]];
      const bool keep = sd[0] >= sd[1];          // stable argsort(-depth)
      const float ra = keep ? r0 : r1;
      const float rb = keep ? r1 : r0;
      rank_c = fmaxf(ra - rb + 1e-4f, 0.f);
      cont_c = fmaxf(fabsf(r0 - q0) - 1e-4f, 0.f)
             + fmaxf(fabsf(r1 - q1) - 1e-4f, 0.f);
      cnt_c = 1.f;
    }
  }

  // wave(64) shuffle reduction, one atomic triple per wave
#pragma unroll
  for (int off = 32; off > 0; off >>= 1) {
    rank_c += __shfl_down(rank_c, off);
    cont_c += __shfl_down(cont_c, off);
    cnt_c  += __shfl_down(cnt_c, off);
  }
  if ((threadIdx.x & 63) == 0) {
    atomicAdd(acc + 0, rank_c);
    atomicAdd(acc + 1, cont_c);
    atomicAdd(acc + 2, cnt_c);
  }
}

// ---------------- Fallback: monolithic (if ws too small) --------------------
__global__ __launch_bounds__(256) void gs_main(
    const float* __restrict__ tgt,
    const float* __restrict__ rnd,
    const int*   __restrict__ vmask,
    float* __restrict__ acc,
    Keys K)
{
  const int i = blockIdx.x * blockDim.x + threadIdx.x;
  float rank_c = 0.f, cont_c = 0.f, cnt_c = 0.f;

  if (i < N_SAMP) {
    const uint32_t ui = (uint32_t)i;
    const uint32_t syb = jrandint(K, 0, ui, 840u);
    const uint32_t sxb = jrandint(K, 1, ui, 1680u);

    int sy[2], sx[2], sidx[2];
    float sd[2];
    bool sm = true;
#pragma unroll
    for (int j = 0; j < 2; j++) {
      sy[j] = (int)(syb + jrandint(K, 2, 2u * ui + (uint32_t)j, 240u));
      sx[j] = (int)(sxb + jrandint(K, 3, 2u * ui + (uint32_t)j, 240u));
      sidx[j] = sy[j] * IMG_W + sx[j];
      sd[j] = tgt[sidx[j]];
      sm = sm && (vmask[sidx[j]] != 0);
    }

    if (sm) {
      int nidx[2];
      bool nm = true;
#pragma unroll
      for (int j = 0; j < 2; j++) {
        const uint32_t nbr = 1u + jrandint(K, 4, 2u * ui + (uint32_t)j, 14u);
        nidx[j] = crop_neighbor(tgt, sy[j], sx[j], sd[j], nbr);
        nm = nm && (vmask[nidx[j]] != 0);
      }
      if (nm) {
        const float r0 = rnd[sidx[0]], r1 = rnd[sidx[1]];
        const float q0 = rnd[nidx[0]], q1 = rnd[nidx[1]];
        const bool keep = sd[0] >= sd[1];
        const float ra = keep ? r0 : r1;
        const float rb = keep ? r1 : r0;
        rank_c = fmaxf(ra - rb + 1e-4f, 0.f);
        cont_c = fmaxf(fabsf(r0 - q0) - 1e-4f, 0.f)
               + fmaxf(fabsf(r1 - q1) - 1e-4f, 0.f);
        cnt_c = 1.f;
      }
    }
  }

#pragma unroll
  for (int off = 32; off > 0; off >>= 1) {
    rank_c += __shfl_down(rank_c, off);
    cont_c += __shfl_down(cont_c, off);
    cnt_c  += __shfl_down(cnt_c, off);
  }
  if ((threadIdx.x & 63) == 0) {
    atomicAdd(acc + 0, rank_c);
    atomicAdd(acc + 1, cont_c);
    atomicAdd(acc + 2, cnt_c);
  }
}

__global__ void gs_finalize(const float* __restrict__ acc, float* __restrict__ out)
{
  const float denom = fmaxf(acc[2], 1.0f);
  out[0] = 0.2f * (acc[0] / denom);                 // WEIGHT * rank_mean
  out[1] = 0.2f * 0.1f * (acc[1] / (denom * 2.0f)); // WEIGHT*CONT_W * cont_mean
}

extern "C" void kernel_launch(void* const* d_in, const int* in_sizes, int n_in,
                              void* d_out, int out_size, void* d_ws, size_t ws_size,
                              hipStream_t stream)
{
  (void)in_sizes; (void)n_in; (void)out_size;
  const float* tgt   = (const float*)d_in[0];
  const float* rnd   = (const float*)d_in[1];
  const int*   vmask = (const int*)d_in[2];
  float* out = (float*)d_out;

  float*    acc    = (float*)d_ws;                       // 3 floats
  uint32_t* wcount = (uint32_t*)d_ws + 3;                // 1 uint
  unsigned long long* wlist =
      (unsigned long long*)((char*)d_ws + 16);           // worklist (8B aligned)

  Keys K;
  compute_keys(K);

  hipMemsetAsync(d_ws, 0, 16, stream);

  const size_t need = 16 + (size_t)N_SAMP * 8;
  const int threads = 256;
  const int blocksA = (N_SAMP + threads - 1) / threads;  // 2025

  if (ws_size >= need) {
    gs_sample<<<blocksA, threads, 0, stream>>>(vmask, wcount, wlist, K);
    gs_crop<<<2048, threads, 0, stream>>>(tgt, rnd, vmask, wcount, wlist, acc, K);
  } else {
    gs_main<<<blocksA, threads, 0, stream>>>(tgt, rnd, vmask, acc, K);
  }
  gs_finalize<<<1, 1, 0, stream>>>(acc, out);
}

// Round 3
// 62.687 us; speedup vs baseline: 6.8783x; 6.8783x over previous
//
#include <hip/hip_runtime.h>
#include <stdint.h>

// ---------------------------------------------------------------------------
// GSDepthRankingLoss on MI355X — R2: single fused kernel with in-block LDS
// compaction (no global worklist / atomic ordering), one crop per thread,
// explicit 7-row register prefetch (56 floats in flight) to hide gather
// latency, 32-bit sort keys. JAX threefry (partitionable) bit-exact (R0/R1).
// ---------------------------------------------------------------------------

#define IMG_W 1920
#define IMG_H 1080
#define N_SAMP 518400         // int(1920*1080*0.25); == 2025 blocks * 256
#define PAD_VAL (-1000000.0f)

struct Keys { uint32_t k[5][2][2]; };  // [randint id][k1|k2][key word]

// Threefry-2x32, 20 rounds (Random123 / JAX-compatible).
static __host__ __device__ inline void tf2x32(uint32_t k0, uint32_t k1,
                                              uint32_t x0, uint32_t x1,
                                              uint32_t& o0, uint32_t& o1)
{
  const uint32_t ks2 = k0 ^ k1 ^ 0x1BD11BDAu;
  x0 += k0; x1 += k1;
#define TFR(r) { x0 += x1; x1 = (x1 << (r)) | (x1 >> (32 - (r))); x1 ^= x0; }
  TFR(13) TFR(15) TFR(26) TFR(6)
  x0 += k1;  x1 += ks2 + 1u;
  TFR(17) TFR(29) TFR(16) TFR(24)
  x0 += ks2; x1 += k0 + 2u;
  TFR(13) TFR(15) TFR(26) TFR(6)
  x0 += k0;  x1 += k1 + 3u;
  TFR(17) TFR(29) TFR(16) TFR(24)
  x0 += k1;  x1 += ks2 + 4u;
  TFR(13) TFR(15) TFR(26) TFR(6)
  x0 += ks2; x1 += k0 + 5u;
#undef TFR
  o0 = x0; o1 = x1;
}

__device__ __forceinline__ uint32_t jrbits(const uint32_t kk[2], uint32_t f)
{
  uint32_t a, b;
  tf2x32(kk[0], kk[1], 0u, f, a, b);   // partitionable: counts = (0, f)
  return a ^ b;                        // 32-bit fold
}

__device__ __forceinline__ uint32_t jrandint(const Keys& K, int r, uint32_t f,
                                             uint32_t span)
{
  const uint32_t hi = jrbits(K.k[r][0], f);
  const uint32_t lo = jrbits(K.k[r][1], f);
  uint32_t m = 65536u % span;
  m = (m * m) % span;
  return ((hi % span) * m + (lo % span)) % span;
}

static void compute_keys(Keys& K)
{
  uint32_t ks[5][2];
  for (uint32_t t = 0; t < 5; t++) {
    uint32_t a, b; tf2x32(0u, 42u, 0u, t, a, b);   // split of key(42)
    ks[t][0] = a; ks[t][1] = b;
  }
  for (int r = 0; r < 5; r++) {                    // randint's internal _split
    uint32_t a, b;
    tf2x32(ks[r][0], ks[r][1], 0u, 0u, a, b); K.k[r][0][0] = a; K.k[r][0][1] = b;
    tf2x32(ks[r][0], ks[r][1], 0u, 1u, a, b); K.k[r][1][0] = a; K.k[r][1][1] = b;
  }
}

// Find the nbr-th nearest neighbour (by |depth - sd|, stable position tie)
// of a 7x7 crop centered at (sy,sx). All 7 rows prefetched to registers
// before any sort work (56 in-flight loads hide gather latency).
__device__ __forceinline__ int crop_neighbor(const float* __restrict__ tgt,
                                             int sy, int sx, float sd,
                                             uint32_t nbr)
{
  float v[7][8];
  const bool interior = (sy >= 3) && (sy <= IMG_H - 4) &&
                        (sx >= 3) && (sx <= IMG_W - 4);
  if (interior) {
    const float* p = tgt + (sy - 3) * IMG_W + (sx - 3);
#pragma unroll
    for (int r = 0; r < 7; r++)
#pragma unroll
      for (int c = 0; c < 8; c++)
        v[r][c] = p[r * IMG_W + c];     // adjacent dwords -> vectorized loads
  } else {
    // rare edge path (~1e-3): guarded scalar loads with PAD semantics
#pragma unroll
    for (int r = 0; r < 7; r++) {
      const int yy = sy - 3 + r;
      const bool rok = (yy >= 0) && (yy < IMG_H);
#pragma unroll
      for (int c = 0; c < 8; c++) {
        const int xx = sx - 3 + c;
        const bool ok = rok && (c < 7) && (xx >= 0) && (xx < IMG_W);
        v[r][c] = ok ? tgt[yy * IMG_W + xx] : PAD_VAL;
      }
    }
  }

  // 15 smallest of 49 unique keys: (|diff|bits & ~63) | pos. Stable ties ==
  // stable argsort. Pads rank >= 16 (>=16 in-bounds cells per crop).
  uint32_t arr[15];
#pragma unroll
  for (int t = 0; t < 15; t++) arr[t] = 0xFFFFFFFFu;

#pragma unroll
  for (int r = 0; r < 7; r++) {
#pragma unroll
    for (int c = 0; c < 7; c++) {
      const int q = r * 7 + c;
      uint32_t key = (__float_as_uint(v[r][c] - sd) & 0x7FFFFFC0u) | (uint32_t)q;
      const int depth = (q + 1 < 15) ? (q + 1) : 15;   // triangular insert
#pragma unroll
      for (int t = 0; t < 15; t++) {
        if (t < depth) {
          const uint32_t lo = min(key, arr[t]);
          const uint32_t hi = max(key, arr[t]);
          arr[t] = lo; key = hi;
        }
      }
    }
  }

  uint32_t relkey = 0;
#pragma unroll
  for (int t = 1; t < 15; t++)
    if ((uint32_t)t == nbr) relkey = arr[t];
  const uint32_t rel = relkey & 63u;
  const int ny = sy - 3 + (int)(rel / 7u);
  const int nx = sx - 3 + (int)(rel % 7u);
  return ny * IMG_W + nx;
}

__global__ __launch_bounds__(256, 2) void gs_fused(
    const float* __restrict__ tgt,
    const float* __restrict__ rnd,
    const int*   __restrict__ vmask,
    float* __restrict__ acc,
    Keys K)
{
  __shared__ unsigned long long ent[256];  // compacted survivor entries
  __shared__ float    res_sd[512];         // per-crop center target depth
  __shared__ int      res_ni[512];         // per-crop neighbour idx (-1 invalid)
  __shared__ uint32_t scnt[4];             // per-wave survivor counts
  __shared__ float    partial[12];         // per-wave reduce partials [4][3]

  const uint32_t tid  = threadIdx.x;
  const uint32_t lane = tid & 63u;
  const uint32_t wave = tid >> 6;
  const uint32_t ui   = blockIdx.x * 256u + tid;   // sample id (grid exact)

  // ---------------- phase A: PRNG + sample mask + LDS compaction ------------
  const uint32_t syb = jrandint(K, 0, ui, 840u);    // H - 240
  const uint32_t sxb = jrandint(K, 1, ui, 1680u);   // W - 240
  const uint32_t sy0 = syb + jrandint(K, 2, 2u * ui,      240u);
  const uint32_t sy1 = syb + jrandint(K, 2, 2u * ui + 1u, 240u);
  const uint32_t sx0 = sxb + jrandint(K, 3, 2u * ui,      240u);
  const uint32_t sx1 = sxb + jrandint(K, 3, 2u * ui + 1u, 240u);
  const bool ok = (vmask[sy0 * IMG_W + sx0] != 0) &&
                  (vmask[sy1 * IMG_W + sx1] != 0);

  const unsigned long long ball = __ballot(ok);
  if (lane == 0) scnt[wave] = (uint32_t)__popcll(ball);
  __syncthreads();

  uint32_t base = 0;
#pragma unroll
  for (uint32_t w = 0; w < 4; w++) if (w < wave) base += scnt[w];
  const uint32_t nsurv = scnt[0] + scnt[1] + scnt[2] + scnt[3];

  if (ok) {
    const uint32_t pos = base + (uint32_t)__popcll(ball & ((1ull << lane) - 1ull));
    ent[pos] = ((unsigned long long)ui  << 44) |
               ((unsigned long long)sy0 << 33) | ((unsigned long long)sx0 << 22) |
               ((unsigned long long)sy1 << 11) |  (unsigned long long)sx1;
  }
  __syncthreads();

  // ---------------- phase B: one 7x7 crop per thread (dense) ----------------
  for (uint32_t t = tid; t < 2u * nsurv; t += 256u) {
    const unsigned long long e = ent[t >> 1];
    const int jj = (int)(t & 1u);
    const uint32_t eui = (uint32_t)(e >> 44);
    const int sy = jj ? (int)((e >> 11) & 2047u) : (int)((e >> 33) & 2047u);
    const int sx = jj ? (int)( e        & 2047u) : (int)((e >> 22) & 2047u);

    const float sd = tgt[sy * IMG_W + sx];
    const uint32_t nbr = 1u + jrandint(K, 4, 2u * eui + (uint32_t)jj, 14u);
    const int nidx = crop_neighbor(tgt, sy, sx, sd, nbr);
    res_sd[t] = sd;
    res_ni[t] = (vmask[nidx] != 0) ? nidx : -1;
  }
  __syncthreads();

  // ---------------- phase C: pair combine + loss -----------------------------
  float rank_c = 0.f, cont_c = 0.f, cnt_c = 0.f;
  for (uint32_t s = tid; s < nsurv; s += 256u) {
    const int n0 = res_ni[2u * s], n1 = res_ni[2u * s + 1u];
    if ((n0 >= 0) && (n1 >= 0)) {
      const unsigned long long e = ent[s];
      const int esy0 = (int)((e >> 33) & 2047u), esx0 = (int)((e >> 22) & 2047u);
      const int esy1 = (int)((e >> 11) & 2047u), esx1 = (int)( e        & 2047u);
      const float r0 = rnd[esy0 * IMG_W + esx0];
      const float r1 = rnd[esy1 * IMG_W + esx1];
      const float q0 = rnd[n0], q1 = rnd[n1];
      const float sd0 = res_sd[2u * s], sd1 = res_sd[2u * s + 1u];
      const bool keep = sd0 >= sd1;            // stable argsort(-depth)
      const float ra = keep ? r0 : r1;
      const float rb = keep ? r1 : r0;
      rank_c += fmaxf(ra - rb + 1e-4f, 0.f);
      cont_c += fmaxf(fabsf(r0 - q0) - 1e-4f, 0.f)
              + fmaxf(fabsf(r1 - q1) - 1e-4f, 0.f);
      cnt_c  += 1.f;
    }
  }

  // ---------------- block reduction: wave shuffles -> LDS -> 3 atomics ------
#pragma unroll
  for (int off = 32; off > 0; off >>= 1) {
    rank_c += __shfl_down(rank_c, off);
    cont_c += __shfl_down(cont_c, off);
    cnt_c  += __shfl_down(cnt_c, off);
  }
  if (lane == 0) {
    partial[wave * 3 + 0] = rank_c;
    partial[wave * 3 + 1] = cont_c;
    partial[wave * 3 + 2] = cnt_c;
  }
  __syncthreads();
  if (tid < 3) {
    const float s = partial[tid] + partial[3 + tid] +
                    partial[6 + tid] + partial[9 + tid];
    atomicAdd(acc + tid, s);
  }
}

__global__ void gs_finalize(const float* __restrict__ acc, float* __restrict__ out)
{
  const float denom = fmaxf(acc[2], 1.0f);
  out[0] = 0.2f * (acc[0] / denom);                 // WEIGHT * rank_mean
  out[1] = 0.2f * 0.1f * (acc[1] / (denom * 2.0f)); // WEIGHT*CONT_W * cont_mean
}

extern "C" void kernel_launch(void* const* d_in, const int* in_sizes, int n_in,
                              void* d_out, int out_size, void* d_ws, size_t ws_size,
                              hipStream_t stream)
{
  (void)in_sizes; (void)n_in; (void)out_size; (void)ws_size;
  const float* tgt   = (const float*)d_in[0];
  const float* rnd   = (const float*)d_in[1];
  const int*   vmask = (const int*)d_in[2];
  float* out = (float*)d_out;
  float* acc = (float*)d_ws;          // 3 floats + pad

  Keys K;
  compute_keys(K);

  hipMemsetAsync(acc, 0, 16, stream);
  gs_fused<<<N_SAMP / 256, 256, 0, stream>>>(tgt, rnd, vmask, acc, K);
  gs_finalize<<<1, 1, 0, stream>>>(acc, out);
}

// Round 4
// 60.417 us; speedup vs baseline: 7.1367x; 1.0376x over previous
//
#include <hip/hip_runtime.h>
#include <stdint.h>

// ---------------------------------------------------------------------------
// GSDepthRankingLoss on MI355X — R3:
//   + bitpacked valid_mask (259KB, L2-resident) via prologue kernel
//   + forced batched crop loads (sched_barrier) to overlap gather latency
//   + 512 samples/block so phase B fills all waves (2*nsurv ~= 256 threads)
// JAX threefry (partitionable) bit-exact (verified R0-R2, absmax 0).
// ---------------------------------------------------------------------------

#define IMG_W 1920
#define IMG_H 1080
#define N_PIX (IMG_W * IMG_H)
#define N_SAMP 518400         // int(1920*1080*0.25)
#define PAD_VAL (-1000000.0f)

struct Keys { uint32_t k[5][2][2]; };  // [randint id][k1|k2][key word]

// Threefry-2x32, 20 rounds (Random123 / JAX-compatible).
static __host__ __device__ inline void tf2x32(uint32_t k0, uint32_t k1,
                                              uint32_t x0, uint32_t x1,
                                              uint32_t& o0, uint32_t& o1)
{
  const uint32_t ks2 = k0 ^ k1 ^ 0x1BD11BDAu;
  x0 += k0; x1 += k1;
#define TFR(r) { x0 += x1; x1 = (x1 << (r)) | (x1 >> (32 - (r))); x1 ^= x0; }
  TFR(13) TFR(15) TFR(26) TFR(6)
  x0 += k1;  x1 += ks2 + 1u;
  TFR(17) TFR(29) TFR(16) TFR(24)
  x0 += ks2; x1 += k0 + 2u;
  TFR(13) TFR(15) TFR(26) TFR(6)
  x0 += k0;  x1 += k1 + 3u;
  TFR(17) TFR(29) TFR(16) TFR(24)
  x0 += k1;  x1 += ks2 + 4u;
  TFR(13) TFR(15) TFR(26) TFR(6)
  x0 += ks2; x1 += k0 + 5u;
#undef TFR
  o0 = x0; o1 = x1;
}

__device__ __forceinline__ uint32_t jrbits(const uint32_t kk[2], uint32_t f)
{
  uint32_t a, b;
  tf2x32(kk[0], kk[1], 0u, f, a, b);   // partitionable: counts = (0, f)
  return a ^ b;                        // 32-bit fold
}

__device__ __forceinline__ uint32_t jrandint(const Keys& K, int r, uint32_t f,
                                             uint32_t span)
{
  const uint32_t hi = jrbits(K.k[r][0], f);
  const uint32_t lo = jrbits(K.k[r][1], f);
  uint32_t m = 65536u % span;
  m = (m * m) % span;
  return ((hi % span) * m + (lo % span)) % span;
}

static void compute_keys(Keys& K)
{
  uint32_t ks[5][2];
  for (uint32_t t = 0; t < 5; t++) {
    uint32_t a, b; tf2x32(0u, 42u, 0u, t, a, b);   // split of key(42)
    ks[t][0] = a; ks[t][1] = b;
  }
  for (int r = 0; r < 5; r++) {                    // randint's internal _split
    uint32_t a, b;
    tf2x32(ks[r][0], ks[r][1], 0u, 0u, a, b); K.k[r][0][0] = a; K.k[r][0][1] = b;
    tf2x32(ks[r][0], ks[r][1], 0u, 1u, a, b); K.k[r][1][0] = a; K.k[r][1][1] = b;
  }
}

// valid test: bit table if available (L2-resident), else raw int mask
__device__ __forceinline__ bool validat(const unsigned long long* __restrict__ vb,
                                        const int* __restrict__ vm, uint32_t idx)
{
  if (vb) return ((vb[idx >> 6] >> (idx & 63u)) & 1ull) != 0ull;
  return vm[idx] != 0;
}

// ---------------- prologue: bitpack valid mask (2073600 -> 259KB) -----------
__global__ __launch_bounds__(256) void gs_bitpack(
    const int* __restrict__ vmask,
    unsigned long long* __restrict__ vbits)
{
  const uint32_t gid = blockIdx.x * 256u + threadIdx.x;   // 8100*256 == N_PIX
  const unsigned long long ball = __ballot(vmask[gid] != 0);
  if ((threadIdx.x & 63u) == 0) vbits[gid >> 6] = ball;
}

// Find the nbr-th nearest neighbour (by |depth - sd|, stable position tie)
// of a 7x7 crop centered at (sy,sx). All 7 rows loaded BEFORE the sort
// (sched_barrier pins the loads above) so gather latency overlaps once.
__device__ __forceinline__ int crop_neighbor(const float* __restrict__ tgt,
                                             int sy, int sx, float sd,
                                             uint32_t nbr)
{
  float v[7][8];
  const bool interior = (sy >= 3) && (sy <= IMG_H - 4) &&
                        (sx >= 3) && (sx <= IMG_W - 5);
  if (interior) {
    const float* p = tgt + (sy - 3) * IMG_W + (sx - 3);
#pragma unroll
    for (int r = 0; r < 7; r++)
      __builtin_memcpy(&v[r][0], p + r * IMG_W, 32);  // 2x dwordx4 per row
  } else {
    // rare edge path (~6e-5 of crops): guarded scalar loads, PAD semantics
#pragma unroll
    for (int r = 0; r < 7; r++) {
      const int yy = sy - 3 + r;
      const bool rok = (yy >= 0) && (yy < IMG_H);
#pragma unroll
      for (int c = 0; c < 8; c++) {
        const int xx = sx - 3 + c;
        const bool okc = rok && (c < 7) && (xx >= 0) && (xx < IMG_W);
        v[r][c] = okc ? tgt[yy * IMG_W + xx] : PAD_VAL;
      }
    }
  }
  __builtin_amdgcn_sched_barrier(0);  // all loads issued before sort work

  // 15 smallest of 49 unique keys: (|diff|bits & ~63) | pos. Stable ties ==
  // stable argsort. Pads rank >= 16 (>=16 in-bounds cells per crop).
  uint32_t arr[15];
#pragma unroll
  for (int t = 0; t < 15; t++) arr[t] = 0xFFFFFFFFu;

#pragma unroll
  for (int r = 0; r < 7; r++) {
#pragma unroll
    for (int c = 0; c < 7; c++) {
      const int q = r * 7 + c;
      uint32_t key = (__float_as_uint(v[r][c] - sd) & 0x7FFFFFC0u) | (uint32_t)q;
      const int depth = (q + 1 < 15) ? (q + 1) : 15;   // triangular insert
#pragma unroll
      for (int t = 0; t < 15; t++) {
        if (t < depth) {
          const uint32_t lo = min(key, arr[t]);
          const uint32_t hi = max(key, arr[t]);
          arr[t] = lo; key = hi;
        }
      }
    }
  }

  uint32_t relkey = 0;
#pragma unroll
  for (int t = 1; t < 15; t++)
    if ((uint32_t)t == nbr) relkey = arr[t];
  const uint32_t rel = relkey & 63u;
  const int ny = sy - 3 + (int)(rel / 7u);
  const int nx = sx - 3 + (int)(rel % 7u);
  return ny * IMG_W + nx;
}

__global__ __launch_bounds__(256, 2) void gs_fused(
    const float* __restrict__ tgt,
    const float* __restrict__ rnd,
    const int*   __restrict__ vmask,
    const unsigned long long* __restrict__ vbits,  // may be nullptr
    float* __restrict__ acc,
    Keys K)
{
  __shared__ unsigned long long ent[512];  // compacted survivor entries
  __shared__ float    res_sd[1024];        // per-crop center target depth
  __shared__ int      res_ni[1024];        // per-crop neighbour idx (-1 invalid)
  __shared__ uint32_t scnt[8];             // per-wave survivor counts (2 rounds)
  __shared__ float    partial[12];         // per-wave reduce partials [4][3]

  const uint32_t tid  = threadIdx.x;
  const uint32_t lane = tid & 63u;
  const uint32_t wave = tid >> 6;

  // ------------- phase A: PRNG + sample mask, 2 samples per thread ----------
  unsigned long long e[2];
  bool ok[2];
#pragma unroll
  for (int h = 0; h < 2; h++) {
    const uint32_t ui = blockIdx.x * 512u + (uint32_t)h * 256u + tid;
    bool o = false;
    unsigned long long ee = 0;
    if (ui < N_SAMP) {
      const uint32_t syb = jrandint(K, 0, ui, 840u);    // H - 240
      const uint32_t sxb = jrandint(K, 1, ui, 1680u);   // W - 240
      const uint32_t sy0 = syb + jrandint(K, 2, 2u * ui,      240u);
      const uint32_t sy1 = syb + jrandint(K, 2, 2u * ui + 1u, 240u);
      const uint32_t sx0 = sxb + jrandint(K, 3, 2u * ui,      240u);
      const uint32_t sx1 = sxb + jrandint(K, 3, 2u * ui + 1u, 240u);
      o = validat(vbits, vmask, sy0 * IMG_W + sx0) &&
          validat(vbits, vmask, sy1 * IMG_W + sx1);
      ee = ((unsigned long long)ui  << 44) |
           ((unsigned long long)sy0 << 33) | ((unsigned long long)sx0 << 22) |
           ((unsigned long long)sy1 << 11) |  (unsigned long long)sx1;
    }
    ok[h] = o; e[h] = ee;
  }

  const unsigned long long b0 = __ballot(ok[0]);
  const unsigned long long b1 = __ballot(ok[1]);
  if (lane == 0) {
    scnt[wave]     = (uint32_t)__popcll(b0);
    scnt[4 + wave] = (uint32_t)__popcll(b1);
  }
  __syncthreads();

  uint32_t base0 = 0, sum0 = 0, base1 = 0, nsurv = 0;
#pragma unroll
  for (uint32_t w = 0; w < 4; w++) {
    if (w < wave) { base0 += scnt[w]; base1 += scnt[4 + w]; }
    sum0  += scnt[w];
    nsurv += scnt[w] + scnt[4 + w];
  }
  base1 += sum0;

  if (ok[0]) ent[base0 + (uint32_t)__popcll(b0 & ((1ull << lane) - 1ull))] = e[0];
  if (ok[1]) ent[base1 + (uint32_t)__popcll(b1 & ((1ull << lane) - 1ull))] = e[1];
  __syncthreads();

  // ------------- phase B: one 7x7 crop per thread (dense, ~2*nsurv=512) -----
  for (uint32_t t = tid; t < 2u * nsurv; t += 256u) {
    const unsigned long long ee = ent[t >> 1];
    const int jj = (int)(t & 1u);
    const uint32_t eui = (uint32_t)(ee >> 44);
    const int sy = jj ? (int)((ee >> 11) & 2047u) : (int)((ee >> 33) & 2047u);
    const int sx = jj ? (int)( ee        & 2047u) : (int)((ee >> 22) & 2047u);

    const float sd = tgt[sy * IMG_W + sx];
    const uint32_t nbr = 1u + jrandint(K, 4, 2u * eui + (uint32_t)jj, 14u);
    const int nidx = crop_neighbor(tgt, sy, sx, sd, nbr);
    res_sd[t] = sd;
    res_ni[t] = validat(vbits, vmask, (uint32_t)nidx) ? nidx : -1;
  }
  __syncthreads();

  // ------------- phase C: pair combine + loss --------------------------------
  float rank_c = 0.f, cont_c = 0.f, cnt_c = 0.f;
  for (uint32_t s = tid; s < nsurv; s += 256u) {
    const int n0 = res_ni[2u * s], n1 = res_ni[2u * s + 1u];
    if ((n0 >= 0) && (n1 >= 0)) {
      const unsigned long long ee = ent[s];
      const int esy0 = (int)((ee >> 33) & 2047u), esx0 = (int)((ee >> 22) & 2047u);
      const int esy1 = (int)((ee >> 11) & 2047u), esx1 = (int)( ee        & 2047u);
      const float r0 = rnd[esy0 * IMG_W + esx0];
      const float r1 = rnd[esy1 * IMG_W + esx1];
      const float q0 = rnd[n0], q1 = rnd[n1];
      const float sd0 = res_sd[2u * s], sd1 = res_sd[2u * s + 1u];
      const bool keep = sd0 >= sd1;            // stable argsort(-depth)
      const float ra = keep ? r0 : r1;
      const float rb = keep ? r1 : r0;
      rank_c += fmaxf(ra - rb + 1e-4f, 0.f);
      cont_c += fmaxf(fabsf(r0 - q0) - 1e-4f, 0.f)
              + fmaxf(fabsf(r1 - q1) - 1e-4f, 0.f);
      cnt_c  += 1.f;
    }
  }

  // ------------- block reduction: wave shuffles -> LDS -> 3 atomics ---------
#pragma unroll
  for (int off = 32; off > 0; off >>= 1) {
    rank_c += __shfl_down(rank_c, off);
    cont_c += __shfl_down(cont_c, off);
    cnt_c  += __shfl_down(cnt_c, off);
  }
  if (lane == 0) {
    partial[wave * 3 + 0] = rank_c;
    partial[wave * 3 + 1] = cont_c;
    partial[wave * 3 + 2] = cnt_c;
  }
  __syncthreads();
  if (tid < 3) {
    const float s = partial[tid] + partial[3 + tid] +
                    partial[6 + tid] + partial[9 + tid];
    atomicAdd(acc + tid, s);
  }
}

__global__ void gs_finalize(const float* __restrict__ acc, float* __restrict__ out)
{
  const float denom = fmaxf(acc[2], 1.0f);
  out[0] = 0.2f * (acc[0] / denom);                 // WEIGHT * rank_mean
  out[1] = 0.2f * 0.1f * (acc[1] / (denom * 2.0f)); // WEIGHT*CONT_W * cont_mean
}

extern "C" void kernel_launch(void* const* d_in, const int* in_sizes, int n_in,
                              void* d_out, int out_size, void* d_ws, size_t ws_size,
                              hipStream_t stream)
{
  (void)in_sizes; (void)n_in; (void)out_size;
  const float* tgt   = (const float*)d_in[0];
  const float* rnd   = (const float*)d_in[1];
  const int*   vmask = (const int*)d_in[2];
  float* out = (float*)d_out;

  float* acc = (float*)d_ws;                                   // 16B
  unsigned long long* vbits = (unsigned long long*)((char*)d_ws + 16);
  const size_t need = 16 + (size_t)(N_PIX / 64) * 8;           // 259,216 B

  Keys K;
  compute_keys(K);

  hipMemsetAsync(acc, 0, 16, stream);

  const bool use_bits = (ws_size >= need);
  if (use_bits)
    gs_bitpack<<<N_PIX / 256, 256, 0, stream>>>(vmask, vbits);

  const int blocksF = (N_SAMP + 511) / 512;   // 1013
  gs_fused<<<blocksF, 256, 0, stream>>>(tgt, rnd, vmask,
                                        use_bits ? vbits : nullptr, acc, K);
  gs_finalize<<<1, 1, 0, stream>>>(acc, out);
}